// Round 1
// baseline (2539.449 us; speedup 1.0000x reference)
//
#include <hip/hip_runtime.h>

// Problem constants (from reference)
#define B_  2
#define S_  2048
#define D_  1024
#define H_  16
#define DH_ 64

// ---------------------------------------------------------------------------
// proj_gemm: C[M,N] = X[M,K] @ W[N,K]^T + bias[N]
// 128x128 block tile, BK=16, 256 threads, 8x8 per thread (split 4+4 groups).
// ---------------------------------------------------------------------------
#define PBM 128
#define PBN 128
#define PBK 16
#define PSTR 129  // LDS row stride (BM+1): bank = (k + m) % 32

__global__ __launch_bounds__(256) void proj_gemm_kernel(
    const float* __restrict__ X, const float* __restrict__ W,
    const float* __restrict__ bias, float* __restrict__ C,
    int M, int N, int K)
{
  __shared__ float As[PBK * PSTR];  // As[k][m]
  __shared__ float Bs[PBK * PSTR];  // Bs[k][n]
  const int tid = threadIdx.x;
  const int tx = tid & 15;   // n dim
  const int ty = tid >> 4;   // m dim
  const int m0 = blockIdx.x * PBM;
  const int n0 = blockIdx.y * PBN;

  float acc[8][8];
#pragma unroll
  for (int i = 0; i < 8; ++i)
#pragma unroll
    for (int j = 0; j < 8; ++j) acc[i][j] = 0.0f;

  for (int kt = 0; kt < K; kt += PBK) {
#pragma unroll
    for (int i = 0; i < 2; ++i) {
      const int f = tid + i * 256;          // [0,512)
      const int row = f >> 2;               // [0,128)
      const int kq = f & 3;                 // float4 idx within 16 cols
      float4 va = *(const float4*)(X + (size_t)(m0 + row) * K + kt + kq * 4);
      As[(kq * 4 + 0) * PSTR + row] = va.x;
      As[(kq * 4 + 1) * PSTR + row] = va.y;
      As[(kq * 4 + 2) * PSTR + row] = va.z;
      As[(kq * 4 + 3) * PSTR + row] = va.w;
      float4 vb = *(const float4*)(W + (size_t)(n0 + row) * K + kt + kq * 4);
      Bs[(kq * 4 + 0) * PSTR + row] = vb.x;
      Bs[(kq * 4 + 1) * PSTR + row] = vb.y;
      Bs[(kq * 4 + 2) * PSTR + row] = vb.z;
      Bs[(kq * 4 + 3) * PSTR + row] = vb.w;
    }
    __syncthreads();
#pragma unroll
    for (int k = 0; k < PBK; ++k) {
      float a[8], b[8];
#pragma unroll
      for (int r = 0; r < 4; ++r) {
        a[r]     = As[k * PSTR + ty * 4 + r];
        a[r + 4] = As[k * PSTR + 64 + ty * 4 + r];
        b[r]     = Bs[k * PSTR + tx * 4 + r];
        b[r + 4] = Bs[k * PSTR + 64 + tx * 4 + r];
      }
#pragma unroll
      for (int i = 0; i < 8; ++i)
#pragma unroll
        for (int j = 0; j < 8; ++j) acc[i][j] = fmaf(a[i], b[j], acc[i][j]);
    }
    __syncthreads();
  }

  // epilogue: + bias, float4 stores
#pragma unroll
  for (int ig = 0; ig < 2; ++ig) {
#pragma unroll
    for (int r = 0; r < 4; ++r) {
      const int m = m0 + ig * 64 + ty * 4 + r;
#pragma unroll
      for (int jg = 0; jg < 2; ++jg) {
        const int n = n0 + jg * 64 + tx * 4;
        float4 o;
        o.x = acc[ig * 4 + r][jg * 4 + 0] + bias[n + 0];
        o.y = acc[ig * 4 + r][jg * 4 + 1] + bias[n + 1];
        o.z = acc[ig * 4 + r][jg * 4 + 2] + bias[n + 2];
        o.w = acc[ig * 4 + r][jg * 4 + 3] + bias[n + 3];
        *(float4*)(C + (size_t)m * N + n) = o;
      }
    }
  }
}

// ---------------------------------------------------------------------------
// scores: raw masked scores tile [64 x 64] per block.
// S[b,h,i,j] = mask[b,i,j] ? dot(Qh[i],Kh[j]) * 0.125 : -1e9
// ---------------------------------------------------------------------------
__global__ __launch_bounds__(256) void scores_kernel(
    const float* __restrict__ Qp, const float* __restrict__ Kp,
    const int* __restrict__ mask, float* __restrict__ attn)
{
  __shared__ float Qs[64 * 65];  // [m][k] stride 65
  __shared__ float Ks[64 * 65];  // [n][k] stride 65
  const int tid = threadIdx.x;
  const int tx = tid & 15;   // j dim
  const int ty = tid >> 4;   // i dim
  const int bh = blockIdx.z;
  const int b = bh >> 4;
  const int h = bh & 15;
  const int i0 = blockIdx.y * 64;
  const int j0 = blockIdx.x * 64;
  const float* Qb = Qp + (size_t)b * S_ * D_ + h * DH_;
  const float* Kb = Kp + (size_t)b * S_ * D_ + h * DH_;

#pragma unroll
  for (int i = 0; i < 4; ++i) {
    const int f = tid + i * 256;    // [0,1024)
    const int row = f >> 4;         // [0,64)
    const int kq = f & 15;
    float4 vq = *(const float4*)(Qb + (size_t)(i0 + row) * D_ + kq * 4);
    Qs[row * 65 + kq * 4 + 0] = vq.x;
    Qs[row * 65 + kq * 4 + 1] = vq.y;
    Qs[row * 65 + kq * 4 + 2] = vq.z;
    Qs[row * 65 + kq * 4 + 3] = vq.w;
    float4 vk = *(const float4*)(Kb + (size_t)(j0 + row) * D_ + kq * 4);
    Ks[row * 65 + kq * 4 + 0] = vk.x;
    Ks[row * 65 + kq * 4 + 1] = vk.y;
    Ks[row * 65 + kq * 4 + 2] = vk.z;
    Ks[row * 65 + kq * 4 + 3] = vk.w;
  }
  __syncthreads();

  float acc[4][4];
#pragma unroll
  for (int r = 0; r < 4; ++r)
#pragma unroll
    for (int c = 0; c < 4; ++c) acc[r][c] = 0.0f;

#pragma unroll
  for (int k = 0; k < 64; ++k) {
    float a[4], b[4];
#pragma unroll
    for (int r = 0; r < 4; ++r) {
      a[r] = Qs[(ty * 4 + r) * 65 + k];
      b[r] = Ks[(tx * 4 + r) * 65 + k];
    }
#pragma unroll
    for (int r = 0; r < 4; ++r)
#pragma unroll
      for (int c = 0; c < 4; ++c) acc[r][c] = fmaf(a[r], b[c], acc[r][c]);
  }

  const int* mrow = mask + (size_t)b * S_ * S_;
  float* Arow = attn + (size_t)bh * S_ * S_;
#pragma unroll
  for (int r = 0; r < 4; ++r) {
    const int i = i0 + ty * 4 + r;
    const int j = j0 + tx * 4;
    int4 mv = *(const int4*)(mrow + (size_t)i * S_ + j);
    float4 o;
    o.x = mv.x ? acc[r][0] * 0.125f : -1e9f;
    o.y = mv.y ? acc[r][1] * 0.125f : -1e9f;
    o.z = mv.z ? acc[r][2] * 0.125f : -1e9f;
    o.w = mv.w ? acc[r][3] * 0.125f : -1e9f;
    *(float4*)(Arow + (size_t)i * S_ + j) = o;
  }
}

// ---------------------------------------------------------------------------
// softmax: one block per row of length S_=2048, in place.
// ---------------------------------------------------------------------------
__global__ __launch_bounds__(256) void softmax_kernel(float* __restrict__ attn)
{
  float* p = attn + (size_t)blockIdx.x * S_;
  const int tid = threadIdx.x;
  float4 v0 = ((const float4*)p)[tid];
  float4 v1 = ((const float4*)p)[tid + 256];

  float m = fmaxf(fmaxf(fmaxf(v0.x, v0.y), fmaxf(v0.z, v0.w)),
                  fmaxf(fmaxf(v1.x, v1.y), fmaxf(v1.z, v1.w)));
#pragma unroll
  for (int off = 32; off > 0; off >>= 1) m = fmaxf(m, __shfl_down(m, off));
  __shared__ float red[4];
  const int lane = tid & 63, w = tid >> 6;
  if (lane == 0) red[w] = m;
  __syncthreads();
  m = fmaxf(fmaxf(red[0], red[1]), fmaxf(red[2], red[3]));
  __syncthreads();

  v0.x = __expf(v0.x - m); v0.y = __expf(v0.y - m);
  v0.z = __expf(v0.z - m); v0.w = __expf(v0.w - m);
  v1.x = __expf(v1.x - m); v1.y = __expf(v1.y - m);
  v1.z = __expf(v1.z - m); v1.w = __expf(v1.w - m);

  float s = v0.x + v0.y + v0.z + v0.w + v1.x + v1.y + v1.z + v1.w;
#pragma unroll
  for (int off = 32; off > 0; off >>= 1) s += __shfl_down(s, off);
  if (lane == 0) red[w] = s;
  __syncthreads();
  s = red[0] + red[1] + red[2] + red[3];

  const float inv = 1.0f / s;
  v0.x *= inv; v0.y *= inv; v0.z *= inv; v0.w *= inv;
  v1.x *= inv; v1.y *= inv; v1.z *= inv; v1.w *= inv;
  ((float4*)p)[tid] = v0;
  ((float4*)p)[tid + 256] = v1;
}

// ---------------------------------------------------------------------------
// context: Ctx[b, i, h*64+d] = sum_j P[b,h,i,j] * Vp[b, j, h*64+d]
// BM=64 (i), BN=64 (d, full head), BK=32 (j).
// ---------------------------------------------------------------------------
__global__ __launch_bounds__(256) void context_kernel(
    const float* __restrict__ attn, const float* __restrict__ Vp,
    float* __restrict__ Ctx)
{
  __shared__ float Ps[64 * 33];  // [m][k] stride 33
  __shared__ float Vs[32 * 65];  // [k][d] stride 65
  const int tid = threadIdx.x;
  const int tx = tid & 15;   // d dim
  const int ty = tid >> 4;   // i dim
  const int bh = blockIdx.z;
  const int b = bh >> 4;
  const int h = bh & 15;
  const int i0 = blockIdx.x * 64;
  const float* Pb = attn + (size_t)bh * S_ * S_;
  const float* Vb = Vp + (size_t)b * S_ * D_ + h * DH_;

  float acc[4][4];
#pragma unroll
  for (int r = 0; r < 4; ++r)
#pragma unroll
    for (int c = 0; c < 4; ++c) acc[r][c] = 0.0f;

  for (int k0 = 0; k0 < S_; k0 += 32) {
#pragma unroll
    for (int i = 0; i < 2; ++i) {
      const int f = tid + i * 256;   // [0,512)
      {
        const int row = f >> 3;      // [0,64)
        const int kq = f & 7;
        float4 vp = *(const float4*)(Pb + (size_t)(i0 + row) * S_ + k0 + kq * 4);
        Ps[row * 33 + kq * 4 + 0] = vp.x;
        Ps[row * 33 + kq * 4 + 1] = vp.y;
        Ps[row * 33 + kq * 4 + 2] = vp.z;
        Ps[row * 33 + kq * 4 + 3] = vp.w;
      }
      {
        const int kk = f >> 4;       // [0,32)
        const int dq = f & 15;
        float4 vv = *(const float4*)(Vb + (size_t)(k0 + kk) * D_ + dq * 4);
        Vs[kk * 65 + dq * 4 + 0] = vv.x;
        Vs[kk * 65 + dq * 4 + 1] = vv.y;
        Vs[kk * 65 + dq * 4 + 2] = vv.z;
        Vs[kk * 65 + dq * 4 + 3] = vv.w;
      }
    }
    __syncthreads();
#pragma unroll
    for (int k = 0; k < 32; ++k) {
      float a[4], b[4];
#pragma unroll
      for (int r = 0; r < 4; ++r) {
        a[r] = Ps[(ty * 4 + r) * 33 + k];
        b[r] = Vs[k * 65 + tx * 4 + r];
      }
#pragma unroll
      for (int r = 0; r < 4; ++r)
#pragma unroll
        for (int c = 0; c < 4; ++c) acc[r][c] = fmaf(a[r], b[c], acc[r][c]);
    }
    __syncthreads();
  }

#pragma unroll
  for (int r = 0; r < 4; ++r) {
    const int m = i0 + ty * 4 + r;
    float4 o;
    o.x = acc[r][0]; o.y = acc[r][1]; o.z = acc[r][2]; o.w = acc[r][3];
    *(float4*)(Ctx + ((size_t)b * S_ + m) * D_ + h * DH_ + tx * 4) = o;
  }
}

// ---------------------------------------------------------------------------
// ln: out = LayerNorm(resid + Yo) * gamma + beta, one block per token row.
// ---------------------------------------------------------------------------
__global__ __launch_bounds__(256) void ln_kernel(
    const float* __restrict__ resid, const float* __restrict__ Yo,
    const float* __restrict__ gamma, const float* __restrict__ beta,
    float* __restrict__ out)
{
  const size_t row = blockIdx.x;
  const float* r = resid + row * D_;
  const float* y = Yo + row * D_;
  const int tid = threadIdx.x;
  float x[4];
  float s = 0.0f;
#pragma unroll
  for (int i = 0; i < 4; ++i) {
    const int j = tid + i * 256;
    x[i] = r[j] + y[j];
    s += x[i];
  }
  __shared__ float red[4];
  const int lane = tid & 63, w = tid >> 6;
#pragma unroll
  for (int off = 32; off > 0; off >>= 1) s += __shfl_down(s, off);
  if (lane == 0) red[w] = s;
  __syncthreads();
  const float mu = (red[0] + red[1] + red[2] + red[3]) * (1.0f / D_);
  __syncthreads();

  float s2 = 0.0f;
#pragma unroll
  for (int i = 0; i < 4; ++i) {
    const float d = x[i] - mu;
    s2 += d * d;
  }
#pragma unroll
  for (int off = 32; off > 0; off >>= 1) s2 += __shfl_down(s2, off);
  if (lane == 0) red[w] = s2;
  __syncthreads();
  const float var = (red[0] + red[1] + red[2] + red[3]) * (1.0f / D_);
  const float rs = rsqrtf(var + 1e-5f);

#pragma unroll
  for (int i = 0; i < 4; ++i) {
    const int j = tid + i * 256;
    out[row * D_ + j] = (x[i] - mu) * rs * gamma[j] + beta[j];
  }
}

// ---------------------------------------------------------------------------
extern "C" void kernel_launch(void* const* d_in, const int* in_sizes, int n_in,
                              void* d_out, int out_size, void* d_ws, size_t ws_size,
                              hipStream_t stream) {
  (void)in_sizes; (void)n_in; (void)out_size; (void)ws_size;
  const float* q    = (const float*)d_in[0];
  const float* k    = (const float*)d_in[1];
  const float* v    = (const float*)d_in[2];
  const int*  mask  = (const int*)d_in[3];
  const float* wq   = (const float*)d_in[4];
  const float* bq   = (const float*)d_in[5];
  const float* wk   = (const float*)d_in[6];
  const float* bk   = (const float*)d_in[7];
  const float* wv   = (const float*)d_in[8];
  const float* bv   = (const float*)d_in[9];
  const float* wo   = (const float*)d_in[10];
  const float* bo   = (const float*)d_in[11];
  const float* gamma= (const float*)d_in[12];
  const float* beta = (const float*)d_in[13];

  const int M = B_ * S_;  // 4096 tokens
  float* ws = (float*)d_ws;
  float* Qp = ws;                       // 4096*1024
  float* Kp = ws + (size_t)M * D_;      // 4096*1024
  float* Vp = ws + (size_t)2 * M * D_;  // 4096*1024
  float* Ctx = Qp;                      // reuse (Qp dead after scores)
  float* Yo  = Kp;                      // reuse (Kp dead after scores)

  float* out  = (float*)d_out;
  float* attn = out + (size_t)M * D_;   // [B,H,S,S]

  dim3 pg(M / PBM, D_ / PBN);           // 32 x 8
  proj_gemm_kernel<<<pg, 256, 0, stream>>>(q, wq, bq, Qp, M, D_, D_);
  proj_gemm_kernel<<<pg, 256, 0, stream>>>(k, wk, bk, Kp, M, D_, D_);
  proj_gemm_kernel<<<pg, 256, 0, stream>>>(v, wv, bv, Vp, M, D_, D_);

  dim3 sg(S_ / 64, S_ / 64, B_ * H_);   // 32 x 32 x 32
  scores_kernel<<<sg, 256, 0, stream>>>(Qp, Kp, mask, attn);

  softmax_kernel<<<dim3(B_ * H_ * S_), 256, 0, stream>>>(attn);

  context_kernel<<<dim3(S_ / 64, 1, B_ * H_), 256, 0, stream>>>(attn, Vp, Ctx);

  proj_gemm_kernel<<<pg, 256, 0, stream>>>(Ctx, wo, bo, Yo, M, D_, D_);

  ln_kernel<<<dim3(M), 256, 0, stream>>>(q, Yo, gamma, beta, out);
}

// Round 2
// 1135.194 us; speedup vs baseline: 2.2370x; 2.2370x over previous
//
#include <hip/hip_runtime.h>
#include <hip/hip_bf16.h>

#define B_  2
#define S_  2048
#define D_  1024
#define H_  16
#define DH_ 64

typedef __attribute__((ext_vector_type(8))) short short8;   // 8 bf16 = 4 VGPR
typedef __attribute__((ext_vector_type(4))) float floatx4;  // MFMA C/D

// ---------------------------------------------------------------------------
// cast fp32 -> bf16 (RNE), 4 elements/thread
// ---------------------------------------------------------------------------
__global__ __launch_bounds__(256) void cast_f2b_kernel(
    const float* __restrict__ x, __hip_bfloat16* __restrict__ y, int n)
{
  int i = (blockIdx.x * 256 + threadIdx.x) * 4;
  if (i >= n) return;
  float4 v = *(const float4*)(x + i);
  union { __hip_bfloat16 h[4]; uint2 u; } cv;
  cv.h[0] = __float2bfloat16(v.x);
  cv.h[1] = __float2bfloat16(v.y);
  cv.h[2] = __float2bfloat16(v.z);
  cv.h[3] = __float2bfloat16(v.w);
  *(uint2*)((ushort*)y + i) = cv.u;
}

// ---------------------------------------------------------------------------
// stage ROWS x 64 bf16 tile into LDS with row stride 72 (144 B: 16B-aligned,
// bank stride 4 -> fragment b128 reads hit the 8-phase floor, no serialization)
// ---------------------------------------------------------------------------
template<int ROWS>
__device__ inline void stage_bf16(const ushort* __restrict__ g, int gstride,
                                  ushort* lds, int tid)
{
#pragma unroll
  for (int i = 0; i < ROWS * 8 / 256; ++i) {
    int f = tid + i * 256;
    int r = f >> 3, c = f & 7;
    uint4 v = *(const uint4*)(g + (size_t)r * gstride + c * 8);
    *(uint4*)(lds + r * 72 + c * 8) = v;
  }
}

// ---------------------------------------------------------------------------
// MFMA GEMM: C[M,N] = A[M,K] @ Wt[N,K]^T + bias  (A, Wt bf16 K-major)
// block 128x64, BK=64, 4 waves (2x2), wave tile 64x32 = 4x2 MFMA tiles.
// ---------------------------------------------------------------------------
template<bool OUT_BF16>
__global__ __launch_bounds__(256) void mfma_gemm_kernel(
    const ushort* __restrict__ A, const ushort* __restrict__ Wt,
    const float* __restrict__ bias, void* __restrict__ Cout,
    int M, int N, int K)
{
  __shared__ ushort As[128 * 72];
  __shared__ ushort Bs[64 * 72];
  const int tid = threadIdx.x;
  const int l = tid & 63, w = tid >> 6;
  const int wm = w >> 1, wn = w & 1;
  const int lr = l & 15, lq = l >> 4;
  const int m0 = blockIdx.x * 128, n0 = blockIdx.y * 64;

  floatx4 acc[4][2];
#pragma unroll
  for (int tm = 0; tm < 4; ++tm)
#pragma unroll
    for (int tn = 0; tn < 2; ++tn) acc[tm][tn] = (floatx4)0.0f;

  for (int kt = 0; kt < K; kt += 64) {
    stage_bf16<128>(A + (size_t)m0 * K + kt, K, As, tid);
    stage_bf16<64>(Wt + (size_t)n0 * K + kt, K, Bs, tid);
    __syncthreads();
#pragma unroll
    for (int s = 0; s < 2; ++s) {
      const int ko = s * 32 + lq * 8;
      short8 b[2];
#pragma unroll
      for (int tn = 0; tn < 2; ++tn)
        b[tn] = *(const short8*)&Bs[(wn * 32 + tn * 16 + lr) * 72 + ko];
#pragma unroll
      for (int tm = 0; tm < 4; ++tm) {
        short8 a = *(const short8*)&As[(wm * 64 + tm * 16 + lr) * 72 + ko];
#pragma unroll
        for (int tn = 0; tn < 2; ++tn)
          acc[tm][tn] = __builtin_amdgcn_mfma_f32_16x16x32_bf16(a, b[tn], acc[tm][tn], 0, 0, 0);
      }
    }
    __syncthreads();
  }

#pragma unroll
  for (int tm = 0; tm < 4; ++tm)
#pragma unroll
    for (int tn = 0; tn < 2; ++tn) {
      const int n = n0 + wn * 32 + tn * 16 + lr;
      const float bv = bias[n];
#pragma unroll
      for (int r = 0; r < 4; ++r) {
        const int m = m0 + wm * 64 + tm * 16 + lq * 4 + r;
        const float val = acc[tm][tn][r] + bv;
        if (OUT_BF16)
          ((__hip_bfloat16*)Cout)[(size_t)m * N + n] = __float2bfloat16(val);
        else
          ((float*)Cout)[(size_t)m * N + n] = val;
      }
    }
}

// ---------------------------------------------------------------------------
// scores: 128x128 tile of masked scaled QK^T per (b,h). K=64, staged once.
// ---------------------------------------------------------------------------
__global__ __launch_bounds__(256) void scores_mfma_kernel(
    const ushort* __restrict__ Qh, const ushort* __restrict__ Kh,
    const int* __restrict__ mask, float* __restrict__ attn)
{
  __shared__ ushort Qs[128 * 72];
  __shared__ ushort Ks[128 * 72];
  const int tid = threadIdx.x;
  const int l = tid & 63, w = tid >> 6;
  const int wm = w >> 1, wn = w & 1;
  const int lr = l & 15, lq = l >> 4;
  const int bh = blockIdx.z, b = bh >> 4, h = bh & 15;
  const int i0 = blockIdx.y * 128, j0 = blockIdx.x * 128;

  stage_bf16<128>(Qh + ((size_t)b * S_ + i0) * D_ + h * DH_, D_, Qs, tid);
  stage_bf16<128>(Kh + ((size_t)b * S_ + j0) * D_ + h * DH_, D_, Ks, tid);
  __syncthreads();

  floatx4 acc[4][4];
#pragma unroll
  for (int tm = 0; tm < 4; ++tm)
#pragma unroll
    for (int tn = 0; tn < 4; ++tn) acc[tm][tn] = (floatx4)0.0f;

#pragma unroll
  for (int s = 0; s < 2; ++s) {
    const int ko = s * 32 + lq * 8;
    short8 a[4], bb[4];
#pragma unroll
    for (int t = 0; t < 4; ++t) {
      a[t]  = *(const short8*)&Qs[(wm * 64 + t * 16 + lr) * 72 + ko];
      bb[t] = *(const short8*)&Ks[(wn * 64 + t * 16 + lr) * 72 + ko];
    }
#pragma unroll
    for (int tm = 0; tm < 4; ++tm)
#pragma unroll
      for (int tn = 0; tn < 4; ++tn)
        acc[tm][tn] = __builtin_amdgcn_mfma_f32_16x16x32_bf16(a[tm], bb[tn], acc[tm][tn], 0, 0, 0);
  }

  const int* mb = mask + (size_t)b * S_ * S_;
  float* ab = attn + (size_t)bh * S_ * S_;
#pragma unroll
  for (int tm = 0; tm < 4; ++tm)
#pragma unroll
    for (int r = 0; r < 4; ++r) {
      const int i = i0 + wm * 64 + tm * 16 + lq * 4 + r;
#pragma unroll
      for (int tn = 0; tn < 4; ++tn) {
        const int j = j0 + wn * 64 + tn * 16 + lr;
        const int mv = mb[(size_t)i * S_ + j];
        ab[(size_t)i * S_ + j] = mv ? acc[tm][tn][r] * 0.125f : -1e9f;
      }
    }
}

// ---------------------------------------------------------------------------
// softmax: one block per row of length 2048, in place (fp32).
// ---------------------------------------------------------------------------
__global__ __launch_bounds__(256) void softmax_kernel(float* __restrict__ attn)
{
  float* p = attn + (size_t)blockIdx.x * S_;
  const int tid = threadIdx.x;
  float4 v0 = ((const float4*)p)[tid];
  float4 v1 = ((const float4*)p)[tid + 256];

  float m = fmaxf(fmaxf(fmaxf(v0.x, v0.y), fmaxf(v0.z, v0.w)),
                  fmaxf(fmaxf(v1.x, v1.y), fmaxf(v1.z, v1.w)));
#pragma unroll
  for (int off = 32; off > 0; off >>= 1) m = fmaxf(m, __shfl_down(m, off));
  __shared__ float red[4];
  const int lane = tid & 63, w = tid >> 6;
  if (lane == 0) red[w] = m;
  __syncthreads();
  m = fmaxf(fmaxf(red[0], red[1]), fmaxf(red[2], red[3]));
  __syncthreads();

  v0.x = __expf(v0.x - m); v0.y = __expf(v0.y - m);
  v0.z = __expf(v0.z - m); v0.w = __expf(v0.w - m);
  v1.x = __expf(v1.x - m); v1.y = __expf(v1.y - m);
  v1.z = __expf(v1.z - m); v1.w = __expf(v1.w - m);

  float s = v0.x + v0.y + v0.z + v0.w + v1.x + v1.y + v1.z + v1.w;
#pragma unroll
  for (int off = 32; off > 0; off >>= 1) s += __shfl_down(s, off);
  if (lane == 0) red[w] = s;
  __syncthreads();
  s = red[0] + red[1] + red[2] + red[3];

  const float inv = 1.0f / s;
  v0.x *= inv; v0.y *= inv; v0.z *= inv; v0.w *= inv;
  v1.x *= inv; v1.y *= inv; v1.z *= inv; v1.w *= inv;
  ((float4*)p)[tid] = v0;
  ((float4*)p)[tid + 256] = v1;
}

// ---------------------------------------------------------------------------
// transpose V head-slices: Vh[b*S+s][h*64+d] -> Vt[(b*16+h)*64+d][s]
// ---------------------------------------------------------------------------
__global__ __launch_bounds__(256) void transpose_v_kernel(
    const ushort* __restrict__ Vh, ushort* __restrict__ Vt)
{
  __shared__ ushort T[64 * 72];
  const int tid = threadIdx.x;
  const int s0 = blockIdx.x * 64;
  const int h = blockIdx.y;
  const int b = blockIdx.z;
  const ushort* src = Vh + ((size_t)b * S_ + s0) * D_ + h * DH_;
#pragma unroll
  for (int i = 0; i < 2; ++i) {
    int f = tid + i * 256;
    int r = f >> 3, c = f & 7;
    *(uint4*)&T[r * 72 + c * 8] = *(const uint4*)(src + (size_t)r * D_ + c * 8);
  }
  __syncthreads();
  ushort* dst = Vt + (size_t)(b * H_ + h) * DH_ * S_ + s0;
#pragma unroll
  for (int i = 0; i < 2; ++i) {
    int f = tid + i * 256;
    int d = f >> 3, sc = f & 7;
    ushort tmp[8];
#pragma unroll
    for (int u = 0; u < 8; ++u) tmp[u] = T[(sc * 8 + u) * 72 + d];
    *(uint4*)(dst + (size_t)d * S_ + sc * 8) = *(uint4*)tmp;
  }
}

// ---------------------------------------------------------------------------
// context: Ctx[b,i,h*64+d] = sum_j P[bh,i,j] * V[b,j,h*64+d]  (MFMA)
// block: 128 i x 64 d, BK(j)=64. P staged fp32->bf16, Vt rows are j-contig.
// ---------------------------------------------------------------------------
__global__ __launch_bounds__(256) void context_mfma_kernel(
    const float* __restrict__ attn, const ushort* __restrict__ Vt,
    __hip_bfloat16* __restrict__ Ctx)
{
  __shared__ ushort Ps[128 * 72];
  __shared__ ushort Vs[64 * 72];
  const int tid = threadIdx.x;
  const int l = tid & 63, w = tid >> 6;
  const int wm = w >> 1, wn = w & 1;
  const int lr = l & 15, lq = l >> 4;
  const int bh = blockIdx.y, b = bh >> 4, h = bh & 15;
  const int i0 = blockIdx.x * 128;
  const float* Pb = attn + (size_t)bh * S_ * S_;
  const ushort* Vb = Vt + (size_t)bh * DH_ * S_;

  floatx4 acc[4][2];
#pragma unroll
  for (int tm = 0; tm < 4; ++tm)
#pragma unroll
    for (int tn = 0; tn < 2; ++tn) acc[tm][tn] = (floatx4)0.0f;

  for (int j0 = 0; j0 < S_; j0 += 64) {
#pragma unroll
    for (int i = 0; i < 8; ++i) {
      int f = tid + i * 256;
      int r = f >> 4, c = f & 15;
      float4 v = *(const float4*)(Pb + (size_t)(i0 + r) * S_ + j0 + c * 4);
      union { __hip_bfloat16 h[4]; uint2 u; } cv;
      cv.h[0] = __float2bfloat16(v.x); cv.h[1] = __float2bfloat16(v.y);
      cv.h[2] = __float2bfloat16(v.z); cv.h[3] = __float2bfloat16(v.w);
      *(uint2*)&Ps[r * 72 + c * 4] = cv.u;
    }
    stage_bf16<64>(Vb + j0, S_, Vs, tid);
    __syncthreads();
#pragma unroll
    for (int s = 0; s < 2; ++s) {
      const int ko = s * 32 + lq * 8;
      short8 bf0 = *(const short8*)&Vs[(wn * 32 + lr) * 72 + ko];
      short8 bf1 = *(const short8*)&Vs[(wn * 32 + 16 + lr) * 72 + ko];
#pragma unroll
      for (int tm = 0; tm < 4; ++tm) {
        short8 a = *(const short8*)&Ps[(wm * 64 + tm * 16 + lr) * 72 + ko];
        acc[tm][0] = __builtin_amdgcn_mfma_f32_16x16x32_bf16(a, bf0, acc[tm][0], 0, 0, 0);
        acc[tm][1] = __builtin_amdgcn_mfma_f32_16x16x32_bf16(a, bf1, acc[tm][1], 0, 0, 0);
      }
    }
    __syncthreads();
  }

#pragma unroll
  for (int tm = 0; tm < 4; ++tm)
#pragma unroll
    for (int tn = 0; tn < 2; ++tn) {
      const int d = wn * 32 + tn * 16 + lr;
#pragma unroll
      for (int r = 0; r < 4; ++r) {
        const int i = i0 + wm * 64 + tm * 16 + lq * 4 + r;
        Ctx[((size_t)b * S_ + i) * D_ + h * DH_ + d] = __float2bfloat16(acc[tm][tn][r]);
      }
    }
}

// ---------------------------------------------------------------------------
// ln: out = LayerNorm(resid + Yo) * gamma + beta
// ---------------------------------------------------------------------------
__global__ __launch_bounds__(256) void ln_kernel(
    const float* __restrict__ resid, const float* __restrict__ Yo,
    const float* __restrict__ gamma, const float* __restrict__ beta,
    float* __restrict__ out)
{
  const size_t row = blockIdx.x;
  const float* r = resid + row * D_;
  const float* y = Yo + row * D_;
  const int tid = threadIdx.x;
  float x[4];
  float s = 0.0f;
#pragma unroll
  for (int i = 0; i < 4; ++i) {
    const int j = tid + i * 256;
    x[i] = r[j] + y[j];
    s += x[i];
  }
  __shared__ float red[4];
  const int lane = tid & 63, w = tid >> 6;
#pragma unroll
  for (int off = 32; off > 0; off >>= 1) s += __shfl_down(s, off);
  if (lane == 0) red[w] = s;
  __syncthreads();
  const float mu = (red[0] + red[1] + red[2] + red[3]) * (1.0f / D_);
  __syncthreads();

  float s2 = 0.0f;
#pragma unroll
  for (int i = 0; i < 4; ++i) {
    const float d = x[i] - mu;
    s2 += d * d;
  }
#pragma unroll
  for (int off = 32; off > 0; off >>= 1) s2 += __shfl_down(s2, off);
  if (lane == 0) red[w] = s2;
  __syncthreads();
  const float var = (red[0] + red[1] + red[2] + red[3]) * (1.0f / D_);
  const float rs = rsqrtf(var + 1e-5f);

#pragma unroll
  for (int i = 0; i < 4; ++i) {
    const int j = tid + i * 256;
    out[row * D_ + j] = (x[i] - mu) * rs * gamma[j] + beta[j];
  }
}

// ---------------------------------------------------------------------------
extern "C" void kernel_launch(void* const* d_in, const int* in_sizes, int n_in,
                              void* d_out, int out_size, void* d_ws, size_t ws_size,
                              hipStream_t stream) {
  (void)in_sizes; (void)n_in; (void)out_size; (void)ws_size;
  const float* q    = (const float*)d_in[0];
  const float* k    = (const float*)d_in[1];
  const float* v    = (const float*)d_in[2];
  const int*  mask  = (const int*)d_in[3];
  const float* wq   = (const float*)d_in[4];
  const float* bq   = (const float*)d_in[5];
  const float* wk   = (const float*)d_in[6];
  const float* bk   = (const float*)d_in[7];
  const float* wv   = (const float*)d_in[8];
  const float* bv   = (const float*)d_in[9];
  const float* wo   = (const float*)d_in[10];
  const float* bo   = (const float*)d_in[11];
  const float* gamma= (const float*)d_in[12];
  const float* beta = (const float*)d_in[13];

  const int M = B_ * S_;  // 4096 tokens
  char* ws = (char*)d_ws;
  const size_t MBy = 1 << 20;
  // lifetime-overlapped layout, 48 MB total:
  ushort* qB  = (ushort*)(ws + 0);          // 8 MB, dead after proj-q -> Vh
  ushort* kB  = (ushort*)(ws + 8 * MBy);    // 8 MB, dead after proj-k -> Vt
  ushort* vB  = (ushort*)(ws + 16 * MBy);   // 8 MB, dead after proj-v -> Ctx
  ushort* wqB = (ushort*)(ws + 24 * MBy);   // 2 MB
  ushort* wkB = (ushort*)(ws + 26 * MBy);
  ushort* wvB = (ushort*)(ws + 28 * MBy);
  ushort* woB = (ushort*)(ws + 30 * MBy);
  ushort* Qh  = (ushort*)(ws + 32 * MBy);   // 8 MB, dead after scores
  ushort* Kh  = (ushort*)(ws + 40 * MBy);   // 8 MB, dead after scores
  ushort* Vh  = qB;
  ushort* Vt  = kB;
  __hip_bfloat16* Ctx = (__hip_bfloat16*)vB;
  float* Yo   = (float*)(ws + 32 * MBy);    // 16 MB over Qh+Kh

  float* out  = (float*)d_out;
  float* attn = out + (size_t)M * D_;       // [B,H,S,S]

  // casts
  cast_f2b_kernel<<<M * D_ / 1024, 256, 0, stream>>>(q, (__hip_bfloat16*)qB, M * D_);
  cast_f2b_kernel<<<M * D_ / 1024, 256, 0, stream>>>(k, (__hip_bfloat16*)kB, M * D_);
  cast_f2b_kernel<<<M * D_ / 1024, 256, 0, stream>>>(v, (__hip_bfloat16*)vB, M * D_);
  cast_f2b_kernel<<<D_ * D_ / 1024, 256, 0, stream>>>(wq, (__hip_bfloat16*)wqB, D_ * D_);
  cast_f2b_kernel<<<D_ * D_ / 1024, 256, 0, stream>>>(wk, (__hip_bfloat16*)wkB, D_ * D_);
  cast_f2b_kernel<<<D_ * D_ / 1024, 256, 0, stream>>>(wv, (__hip_bfloat16*)wvB, D_ * D_);
  cast_f2b_kernel<<<D_ * D_ / 1024, 256, 0, stream>>>(wo, (__hip_bfloat16*)woB, D_ * D_);

  // projections (bf16 out)
  dim3 pg(M / 128, D_ / 64);  // 32 x 16
  mfma_gemm_kernel<true><<<pg, 256, 0, stream>>>(qB, wqB, bq, Qh, M, D_, D_);
  mfma_gemm_kernel<true><<<pg, 256, 0, stream>>>(kB, wkB, bk, Kh, M, D_, D_);
  mfma_gemm_kernel<true><<<pg, 256, 0, stream>>>(vB, wvB, bv, Vh, M, D_, D_);

  transpose_v_kernel<<<dim3(S_ / 64, H_, B_), 256, 0, stream>>>(Vh, Vt);

  scores_mfma_kernel<<<dim3(S_ / 128, S_ / 128, B_ * H_), 256, 0, stream>>>(Qh, Kh, mask, attn);

  softmax_kernel<<<dim3(B_ * H_ * S_), 256, 0, stream>>>(attn);

  context_mfma_kernel<<<dim3(S_ / 128, B_ * H_), 256, 0, stream>>>(attn, Vt, Ctx);

  mfma_gemm_kernel<false><<<pg, 256, 0, stream>>>((const ushort*)Ctx, woB, bo, Yo, M, D_, D_);

  ln_kernel<<<dim3(M), 256, 0, stream>>>(q, Yo, gamma, beta, out);
}